// Round 2
// baseline (1310.620 us; speedup 1.0000x reference)
//
#include <hip/hip_runtime.h>

// DiscreteLayer (VQ-VAE quantize + EMA codebook stats), MI355X gfx950.
// x: [B=64, D=256, L=4096] fp32. embed: [D, K=32]. Outputs (flat concat):
//   quantize^T [B,D,L] (67108864 f32), embed_out [D,K] (8192), loss (1).
//
// Argmin correctness: fp32 fast path; if (2nd-best - best) gap < GAP_THRESH,
// recompute c_k = ||e_k||^2 - 2 f.e_k in fp64 (fp32->fp64 products are exact,
// so this matches a float64 reference's argmin). ||f||^2 is common across k
// and cannot flip the argmin.

constexpr int   Kc  = 32;
constexpr int   Dc  = 256;
constexpr int   Bc  = 64;
constexpr int   Lc  = 4096;
constexpr int   Nc  = Bc * Lc;               // 262144 points
constexpr long  QSIZE = (long)Bc * Dc * Lc;  // 67108864
constexpr float DECAYf = 0.99f;
constexpr float EPSf   = 1e-5f;
constexpr float GAP_THRESH = 0.02f;          // >> 2x fp32 c_k error bound (~6e-3)

// Workspace layout (floats):
//  [0]                      loss accumulator
//  [8 .. 8+NREP*K)          counts replicas
//  [512 .. 512+NREP*D*K)    embed_sum replicas
constexpr int WS_LOSS   = 0;
constexpr int WS_COUNTS = 8;
constexpr int WS_ESUM   = 512;
constexpr int NREP      = 8;
constexpr size_t WS_FLOATS = WS_ESUM + (size_t)NREP * Dc * Kc;

__global__ __launch_bounds__(256, 4) void vq_main(
    const float* __restrict__ x, const float* __restrict__ embed,
    float* __restrict__ out_q, float* __restrict__ ws)
{
    __shared__ float  s_esq[Kc];
    __shared__ double s_esqd[Kc];
    __shared__ float  s_sum[Dc * Kc];   // 32 KB per-block embed_sum accumulator
    __shared__ float  s_hist[Kc];
    __shared__ float  s_red[4];

    const int tid = threadIdx.x;

    // zero per-block accumulators
    for (int j = tid; j < Dc * Kc; j += 256) s_sum[j] = 0.f;
    if (tid < Kc) {
        s_hist[tid] = 0.f;
        // ||e_k||^2 for k = tid, in fp64 (exact: fp32 squares are exact in fp64)
        double acc = 0.0;
        for (int d = 0; d < Dc; ++d) {
            double e = (double)embed[d * Kc + tid];
            acc = fma(e, e, acc);
        }
        s_esqd[tid] = acc;
        s_esq[tid]  = (float)acc;
    }
    __syncthreads();

    const int p = blockIdx.x * 256 + tid;   // point index, grid == N exactly
    const int b = p >> 12;                  // / L
    const int l = p & (Lc - 1);             // % L
    const float* xcol = x + (size_t)b * Dc * Lc + l;   // element d at xcol[d*L]

    // ---- Phase 1: dot products vs all K codes (embed rows are wave-uniform
    //      -> scalar loads). ----
    float dot[Kc];
    #pragma unroll
    for (int k = 0; k < Kc; ++k) dot[k] = 0.f;

    #pragma unroll 4
    for (int d = 0; d < Dc; ++d) {
        float f = xcol[(size_t)d * Lc];
        const float* er = embed + d * Kc;
        #pragma unroll
        for (int k = 0; k < Kc; ++k) dot[k] = fmaf(f, er[k], dot[k]);
    }

    // argmin over c_k = ||e_k||^2 - 2 dot_k (first occurrence, like jnp.argmin)
    int   kstar  = 0;
    float best   = 3.4e38f;
    float second = 3.4e38f;
    #pragma unroll
    for (int k = 0; k < Kc; ++k) {
        float c = fmaf(-2.0f, dot[k], s_esq[k]);
        if (c < best)        { second = best; best = c; kstar = k; }
        else if (c < second) { second = c; }
    }

    // Exact fp64 recompute for near-ties (rare: ~1e-3 of points)
    if (second - best < GAP_THRESH) {
        double bestd = 1e300;
        int    kb    = 0;
        for (int k = 0; k < Kc; ++k) {
            double acc = 0.0;
            for (int d = 0; d < Dc; ++d) {
                acc = fma((double)xcol[(size_t)d * Lc],
                          (double)embed[d * Kc + k], acc);
            }
            double c = fma(-2.0, acc, s_esqd[k]);
            if (c < bestd) { bestd = c; kb = k; }
        }
        kstar = kb;
    }

    // ---- Phase 2: write quantize, loss, per-block scatter of f into sums ----
    float* ocol = out_q + (size_t)b * Dc * Lc + l;
    float lacc = 0.f;
    for (int d = 0; d < Dc; ++d) {
        float f = xcol[(size_t)d * Lc];            // re-read: L2/L3-resident
        float q = embed[d * Kc + kstar];           // gather within 128B/row
        ocol[(size_t)d * Lc] = q;                  // coalesced column write
        float r = q - f;
        lacc = fmaf(r, r, lacc);
        atomicAdd(&s_sum[d * Kc + kstar], f);      // bank = kstar, ~2-way
    }
    atomicAdd(&s_hist[kstar], 1.0f);

    // loss: wave reduce -> block reduce -> one global atomic per block
    #pragma unroll
    for (int off = 32; off > 0; off >>= 1) lacc += __shfl_down(lacc, off);
    if ((tid & 63) == 0) s_red[tid >> 6] = lacc;
    __syncthreads();   // also orders s_sum/s_hist atomics before flush

    if (tid == 0) {
        atomicAdd(&ws[WS_LOSS], s_red[0] + s_red[1] + s_red[2] + s_red[3]);
    }
    const int rep = blockIdx.x & (NREP - 1);
    float* esum = ws + WS_ESUM + (size_t)rep * Dc * Kc;
    for (int j = tid; j < Dc * Kc; j += 256) atomicAdd(&esum[j], s_sum[j]);
    if (tid < Kc) atomicAdd(&ws[WS_COUNTS + rep * Kc + tid], s_hist[tid]);
}

__global__ void vq_finalize(
    const float* __restrict__ embed,
    const float* __restrict__ cluster_number,
    const float* __restrict__ embed_avg,
    const int*   __restrict__ training,
    const float* __restrict__ ws,
    float* __restrict__ out)
{
    const int j = blockIdx.x * 256 + threadIdx.x;   // 0 .. D*K-1
    if (j >= Dc * Kc) return;
    const int k = j & (Kc - 1);

    // cluster_number EMA + normalization constants (redundant per thread; tiny)
    float n = 0.f, cn_k = 0.f;
    for (int kk = 0; kk < Kc; ++kk) {
        float c = 0.f;
        for (int r = 0; r < NREP; ++r) c += ws[WS_COUNTS + r * Kc + kk];
        float cnew = DECAYf * cluster_number[kk] + (1.0f - DECAYf) * c;
        n += cnew;
        if (kk == k) cn_k = cnew;
    }
    float cn = (cn_k + EPSf) / (n + Kc * EPSf) * n;

    float s = 0.f;
    for (int r = 0; r < NREP; ++r) s += ws[WS_ESUM + (size_t)r * Dc * Kc + j];
    float avg = DECAYf * embed_avg[j] + (1.0f - DECAYf) * s;

    out[QSIZE + j] = (*training) ? (avg / cn) : embed[j];

    if (j == 0) {
        out[QSIZE + Dc * Kc] = ws[WS_LOSS] / (float)QSIZE;  // mean over B*L*D
    }
}

extern "C" void kernel_launch(void* const* d_in, const int* in_sizes, int n_in,
                              void* d_out, int out_size, void* d_ws, size_t ws_size,
                              hipStream_t stream)
{
    (void)in_sizes; (void)n_in; (void)out_size; (void)ws_size;
    const float* x              = (const float*)d_in[0];
    const float* embed          = (const float*)d_in[1];
    const float* cluster_number = (const float*)d_in[2];
    const float* embed_avg      = (const float*)d_in[3];
    const int*   training       = (const int*)d_in[4];
    float* out = (float*)d_out;
    float* ws  = (float*)d_ws;

    hipMemsetAsync(d_ws, 0, WS_FLOATS * sizeof(float), stream);
    vq_main<<<Nc / 256, 256, 0, stream>>>(x, embed, out, ws);
    vq_finalize<<<(Dc * Kc + 255) / 256, 256, 0, stream>>>(
        embed, cluster_number, embed_avg, training, ws, out);
}